// Round 1
// baseline (1113.669 us; speedup 1.0000x reference)
//
#include <hip/hip_runtime.h>
#include <hip/hip_bf16.h>

// Shapes (fixed by the problem)
#define T_DIM 4
#define B_DIM 32
#define N_DIM 196
#define C_DIM 512
#define H_DIM 8
#define D_DIM 64
#define NC 100352       // N_DIM * C_DIM
#define TB 128          // T_DIM * B_DIM
#define M_ROWS 25088    // TB * N_DIM
#define BNC 3211264     // B_DIM * NC

// ---------------------------------------------------------------------------
// GEMM: C[M,512] = A[M,512] @ W[512,512]^T (+ optional bias)
// 64x64 tile, BK=16, 256 threads, 4x4 microtile per thread. fp32.
// M is always a multiple of 64 (25088 = 392*64), N = 512 = 8*64.
// ---------------------------------------------------------------------------
template <bool BIAS>
__global__ __launch_bounds__(256) void gemm_nt(const float* __restrict__ A,
                                               const float* __restrict__ W,
                                               const float* __restrict__ bias,
                                               float* __restrict__ C) {
    __shared__ float As[16][68];  // [k][m], padded row stride 68 (16B aligned, bank-friendly)
    __shared__ float Bs[16][68];  // [k][n]
    const int tid = threadIdx.x;
    const int bm = blockIdx.x * 64;
    const int bn = blockIdx.y * 64;
    const int lr = tid >> 2;          // 0..63 : row within tile for loading
    const int lk = (tid & 3) << 2;    // 0,4,8,12 : k offset for loading (float4)
    const int tm = (tid >> 4) << 2;   // 0..60 step 4 : row base for compute
    const int tn = (tid & 15) << 2;   // 0..60 step 4 : col base for compute

    float acc[4][4] = {};
    const float* Arow = A + (size_t)(bm + lr) * 512 + lk;
    const float* Wrow = W + (size_t)(bn + lr) * 512 + lk;

    for (int k0 = 0; k0 < 512; k0 += 16) {
        const float4 a4 = *reinterpret_cast<const float4*>(Arow + k0);
        const float4 b4 = *reinterpret_cast<const float4*>(Wrow + k0);
        As[lk + 0][lr] = a4.x; As[lk + 1][lr] = a4.y;
        As[lk + 2][lr] = a4.z; As[lk + 3][lr] = a4.w;
        Bs[lk + 0][lr] = b4.x; Bs[lk + 1][lr] = b4.y;
        Bs[lk + 2][lr] = b4.z; Bs[lk + 3][lr] = b4.w;
        __syncthreads();
#pragma unroll
        for (int k = 0; k < 16; ++k) {
            float av[4], bv[4];
#pragma unroll
            for (int i = 0; i < 4; ++i) av[i] = As[k][tm + i];
#pragma unroll
            for (int j = 0; j < 4; ++j) bv[j] = Bs[k][tn + j];
#pragma unroll
            for (int i = 0; i < 4; ++i)
#pragma unroll
                for (int j = 0; j < 4; ++j)
                    acc[i][j] = fmaf(av[i], bv[j], acc[i][j]);
        }
        __syncthreads();
    }

#pragma unroll
    for (int i = 0; i < 4; ++i) {
        float4 o;
        o.x = acc[i][0]; o.y = acc[i][1]; o.z = acc[i][2]; o.w = acc[i][3];
        if (BIAS) {
            o.x += bias[bn + tn + 0];
            o.y += bias[bn + tn + 1];
            o.z += bias[bn + tn + 2];
            o.w += bias[bn + tn + 3];
        }
        *reinterpret_cast<float4*>(&C[(size_t)(bm + tm + i) * 512 + bn + tn]) = o;
    }
}

// ---------------------------------------------------------------------------
// LIF recurrence over `steps` along the leading dim; one thread per state
// element. v <- v + (x - v)*sg ; spike = (h >= 1) ; hard reset v=0.
// Uses _rn intrinsics to forbid FMA contraction (match reference formula).
// Works in-place (S == U) since each element reads before writing.
// ---------------------------------------------------------------------------
template <typename OutT>
__global__ __launch_bounds__(256) void lif_seq(const float* __restrict__ U,
                                               OutT* __restrict__ S,
                                               const float* __restrict__ wptr,
                                               int steps, int stride) {
    const int i = blockIdx.x * 256 + threadIdx.x;
    if (i >= stride) return;
    const float sg = 1.0f / (1.0f + expf(-wptr[0]));
    float v = 0.0f;
    for (int t = 0; t < steps; ++t) {
        const float x = U[(size_t)t * stride + i];
        const float h = __fadd_rn(v, __fmul_rn(__fsub_rn(x, v), sg));
        const bool sp = (h >= 1.0f);
        S[(size_t)t * stride + i] = (OutT)(sp ? 1.0f : 0.0f);
        v = sp ? 0.0f : h;
    }
}

// ---------------------------------------------------------------------------
// Attention per (tb, h) block. Spikes are binary -> everything is exact
// integer math, so (q@k^T)@v == q@(k^T@v) bit-exactly.
//   G[d1][d2] = sum_m k[m,d1]*v[m,d2]  via column bitmmasks + popcount
//   y[r][e]   = sum_{d1: q[r,d1]=1} G[d1][e]
// Output written in the reference's swapaxes(3,4).reshape scrambled layout:
//   f = h*12544 + e*196 + r ; Y[tb*NC + f] = y*0.125
// ---------------------------------------------------------------------------
__global__ __launch_bounds__(256) void attn_kernel(const ushort* __restrict__ Q,
                                                   const ushort* __restrict__ K,
                                                   const ushort* __restrict__ V,
                                                   float* __restrict__ Y) {
    const int tb = blockIdx.x >> 3;
    const int h = blockIdx.x & 7;
    const int tid = threadIdx.x;
    const int wave = tid >> 6;
    const int lane = tid & 63;

    __shared__ unsigned long long qrow[256], krow[256], vrow[256];  // bits over d
    __shared__ unsigned long long kcol[64][4], vcol[64][4];         // bits over m
    __shared__ float G[64][64];
    __shared__ float ybuf[196][65];

    const ushort* qb = Q + (size_t)tb * NC + h * 64;
    const ushort* kb = K + (size_t)tb * NC + h * 64;
    const ushort* vb = V + (size_t)tb * NC + h * 64;

    if (tid >= 196) { qrow[tid] = 0; krow[tid] = 0; vrow[tid] = 0; }

    // Stage rows as 64-bit masks (lane = d). bf16 spike != 0 <=> raw != 0.
    for (int m = wave; m < 196; m += 4) {
        const bool bq = qb[(size_t)m * 512 + lane] != 0;
        const bool bk = kb[(size_t)m * 512 + lane] != 0;
        const bool bv = vb[(size_t)m * 512 + lane] != 0;
        const unsigned long long mq = __ballot(bq);
        const unsigned long long mk = __ballot(bk);
        const unsigned long long mv = __ballot(bv);
        if (lane == 0) { qrow[m] = mq; krow[m] = mk; vrow[m] = mv; }
    }
    __syncthreads();

    // Transpose k,v row masks -> column masks (bits over m, 4 words of 64)
    {
        const int d = tid & 63, j = tid >> 6;
        unsigned long long kc = 0, vc = 0;
#pragma unroll 8
        for (int i2 = 0; i2 < 64; ++i2) {
            kc |= ((krow[j * 64 + i2] >> d) & 1ull) << i2;
            vc |= ((vrow[j * 64 + i2] >> d) & 1ull) << i2;
        }
        kcol[d][j] = kc; vcol[d][j] = vc;
    }
    __syncthreads();

    // G = k^T @ v via popcount (exact integers <= 196)
    for (int p = tid; p < 4096; p += 256) {
        const int d1 = p >> 6, d2 = p & 63;
        const int g = __popcll(kcol[d1][0] & vcol[d2][0]) +
                      __popcll(kcol[d1][1] & vcol[d2][1]) +
                      __popcll(kcol[d1][2] & vcol[d2][2]) +
                      __popcll(kcol[d1][3] & vcol[d2][3]);
        G[d1][d2] = (float)g;
    }
    __syncthreads();

    // y = q @ G : wave handles one row r, lane = e. qm is wave-uniform.
    for (int r = wave; r < 196; r += 4) {
        const unsigned long long qm = qrow[r];
        float acc = 0.0f;
        for (int d1 = 0; d1 < 64; ++d1) {
            if ((qm >> d1) & 1ull) acc += G[d1][lane];
        }
        ybuf[r][lane] = acc;
    }
    __syncthreads();

    // Coalesced scrambled write: f = h*12544 + e*196 + r
    const size_t base = (size_t)tb * NC + (size_t)h * 12544;
    for (int f = tid; f < 12544; f += 256) {
        const int e = f / 196;
        const int r = f - e * 196;
        Y[base + f] = ybuf[r][e] * 0.125f;
    }
}

// ---------------------------------------------------------------------------
// Workspace layout (total 179,830,784 bytes):
//   u    : fp32 [128][196][512]  51,380,224 B  (reused: Q/K/V GEMM out, proj GEMM out)
//   qs   : bf16 spikes           25,690,112 B
//   ks   : bf16 spikes           25,690,112 B
//   vs   : bf16 spikes           25,690,112 B
//   ySc  : fp32 [T][B][N][C]     51,380,224 B  (attention out, attn_lif in-place)
// ---------------------------------------------------------------------------
extern "C" void kernel_launch(void* const* d_in, const int* in_sizes, int n_in,
                              void* d_out, int out_size, void* d_ws, size_t ws_size,
                              hipStream_t stream) {
    const float* x  = (const float*)d_in[0];
    const float* Wq = (const float*)d_in[1];
    const float* Wk = (const float*)d_in[2];
    const float* Wv = (const float*)d_in[3];
    const float* Wp = (const float*)d_in[4];
    const float* bp = (const float*)d_in[5];
    const float* wq = (const float*)d_in[6];
    const float* wk = (const float*)d_in[7];
    const float* wv = (const float*)d_in[8];
    const float* wa = (const float*)d_in[9];
    const float* wp = (const float*)d_in[10];
    float* out = (float*)d_out;

    char* ws = (char*)d_ws;
    float*  u   = (float*)ws;
    ushort* qs  = (ushort*)(ws + 51380224);
    ushort* ks  = (ushort*)(ws + 51380224 + (size_t)25690112);
    ushort* vs  = (ushort*)(ws + 51380224 + (size_t)2 * 25690112);
    float*  ySc = (float*)(ws + 51380224 + (size_t)3 * 25690112);

    const dim3 gGemm(392, 8);
    const dim3 b256(256);

    // Q branch
    gemm_nt<false><<<gGemm, b256, 0, stream>>>(x, Wq, nullptr, u);
    lif_seq<__hip_bfloat16><<<392, 256, 0, stream>>>(u, (__hip_bfloat16*)qs, wq, 128, NC);
    // K branch
    gemm_nt<false><<<gGemm, b256, 0, stream>>>(x, Wk, nullptr, u);
    lif_seq<__hip_bfloat16><<<392, 256, 0, stream>>>(u, (__hip_bfloat16*)ks, wk, 128, NC);
    // V branch
    gemm_nt<false><<<gGemm, b256, 0, stream>>>(x, Wv, nullptr, u);
    lif_seq<__hip_bfloat16><<<392, 256, 0, stream>>>(u, (__hip_bfloat16*)vs, wv, 128, NC);

    // Attention (exact integer path) -> scrambled layout
    attn_kernel<<<1024, 256, 0, stream>>>(qs, ks, vs, ySc);

    // attn_lif over T=4 steps, state [B,N,C], in place (exact arithmetic)
    lif_seq<float><<<12544, 256, 0, stream>>>(ySc, ySc, wa, 4, BNC);

    // Projection + bias, then proj_lif over 128 steps -> output
    gemm_nt<true><<<gGemm, b256, 0, stream>>>(ySc, Wp, bp, u);
    lif_seq<float><<<392, 256, 0, stream>>>(u, out, wp, 128, NC);
}

// Round 2
// 1011.517 us; speedup vs baseline: 1.1010x; 1.1010x over previous
//
#include <hip/hip_runtime.h>
#include <hip/hip_bf16.h>

// Shapes (fixed by the problem)
#define NC 100352       // N*C = 196*512
#define BNC 3211264     // B*N*C
typedef unsigned long long ull;

// ---------------------------------------------------------------------------
// GEMM: C[M,512] = A[M,512] @ W[512,512]^T (+ optional bias)
// 128x128 tile, BK=16, 256 threads, 8x8 microtile (4+4 split at +64 rows/cols
// for conflict-free ds_read_b128). fp32, k-sequential accumulation (bit-
// identical to the round-1 kernel that validated absmax==0).
// ---------------------------------------------------------------------------
template <bool BIAS>
__global__ __launch_bounds__(256) void gemm_nt(const float* __restrict__ A,
                                               const float* __restrict__ W,
                                               const float* __restrict__ bias,
                                               float* __restrict__ C) {
    __shared__ float As[16][132];
    __shared__ float Bs[16][132];
    const int tid = threadIdx.x;
    const int bm = blockIdx.y * 128;
    const int bn = blockIdx.x * 128;
    const int r0 = tid >> 2;         // 0..63 load row (and +64)
    const int kq = (tid & 3) << 2;   // 0,4,8,12 k-offset for float4 load
    const int rg = (tid >> 4) << 2;  // 0..60 compute row base
    const int cg = (tid & 15) << 2;  // 0..60 compute col base

    float acc[8][8] = {};
    const float* A0 = A + (size_t)(bm + r0) * 512 + kq;
    const float* A1 = A0 + (size_t)64 * 512;
    const float* W0 = W + (size_t)(bn + r0) * 512 + kq;
    const float* W1 = W0 + (size_t)64 * 512;

    for (int k0 = 0; k0 < 512; k0 += 16) {
        const float4 a0 = *(const float4*)(A0 + k0);
        const float4 a1 = *(const float4*)(A1 + k0);
        const float4 b0 = *(const float4*)(W0 + k0);
        const float4 b1 = *(const float4*)(W1 + k0);
        __syncthreads();  // previous iteration's LDS reads done
        As[kq + 0][r0] = a0.x; As[kq + 1][r0] = a0.y; As[kq + 2][r0] = a0.z; As[kq + 3][r0] = a0.w;
        As[kq + 0][r0 + 64] = a1.x; As[kq + 1][r0 + 64] = a1.y; As[kq + 2][r0 + 64] = a1.z; As[kq + 3][r0 + 64] = a1.w;
        Bs[kq + 0][r0] = b0.x; Bs[kq + 1][r0] = b0.y; Bs[kq + 2][r0] = b0.z; Bs[kq + 3][r0] = b0.w;
        Bs[kq + 0][r0 + 64] = b1.x; Bs[kq + 1][r0 + 64] = b1.y; Bs[kq + 2][r0 + 64] = b1.z; Bs[kq + 3][r0 + 64] = b1.w;
        __syncthreads();
#pragma unroll
        for (int k = 0; k < 16; ++k) {
            float av[8], bv[8];
            *(float4*)&av[0] = *(const float4*)&As[k][rg];
            *(float4*)&av[4] = *(const float4*)&As[k][rg + 64];
            *(float4*)&bv[0] = *(const float4*)&Bs[k][cg];
            *(float4*)&bv[4] = *(const float4*)&Bs[k][cg + 64];
#pragma unroll
            for (int i = 0; i < 8; ++i)
#pragma unroll
                for (int j = 0; j < 8; ++j)
                    acc[i][j] = fmaf(av[i], bv[j], acc[i][j]);
        }
    }

#pragma unroll
    for (int ih = 0; ih < 2; ++ih)
#pragma unroll
        for (int i = 0; i < 4; ++i) {
            const int row = bm + rg + i + ih * 64;
#pragma unroll
            for (int jh = 0; jh < 2; ++jh) {
                const int col = bn + cg + jh * 64;
                float4 o;
                o.x = acc[ih * 4 + i][jh * 4 + 0];
                o.y = acc[ih * 4 + i][jh * 4 + 1];
                o.z = acc[ih * 4 + i][jh * 4 + 2];
                o.w = acc[ih * 4 + i][jh * 4 + 3];
                if (BIAS) {
                    o.x += bias[col + 0]; o.y += bias[col + 1];
                    o.z += bias[col + 2]; o.w += bias[col + 3];
                }
                *(float4*)&C[(size_t)row * 512 + col] = o;
            }
        }
}

// ---------------------------------------------------------------------------
// LIF recurrence. MODE 0: write float spikes to S. MODE 1: write only 64-bit
// spike masks (lane = d within head); mask index = t*1568 + h*196 + n.
// _rn intrinsics forbid FMA contraction (match reference formula exactly).
// ---------------------------------------------------------------------------
template <int MODE>
__global__ __launch_bounds__(256) void lif_seq(const float* __restrict__ U,
                                               float* __restrict__ S,
                                               ull* __restrict__ M,
                                               const float* __restrict__ wptr,
                                               int steps, int stride) {
    const int i = blockIdx.x * 256 + threadIdx.x;
    if (i >= stride) return;
    const float sg = 1.0f / (1.0f + expf(-wptr[0]));
    const int widx = ((i >> 6) & 7) * 196 + (i >> 9);  // h*196 + n (MODE 1)
    float v = 0.0f;
    for (int t = 0; t < steps; ++t) {
        const float x = U[(size_t)t * stride + i];
        const float h = __fadd_rn(v, __fmul_rn(__fsub_rn(x, v), sg));
        const bool sp = (h >= 1.0f);
        if (MODE == 0) {
            S[(size_t)t * stride + i] = sp ? 1.0f : 0.0f;
        } else {
            const ull m = __ballot(sp);
            if ((threadIdx.x & 63) == 0) M[(size_t)t * 1568 + widx] = m;
        }
        v = sp ? 0.0f : h;
    }
}

// ---------------------------------------------------------------------------
// Attention per (tb, h). Exact integer path:
//   G = k^T v (popcount over row bitmasks), y = q @ G (branch-free integer
//   mad over G rows), output scrambled f = h*12544 + e*196 + r, *0.125.
// ---------------------------------------------------------------------------
__global__ __launch_bounds__(256) void attn_kernel(const ull* __restrict__ Qm,
                                                   const ull* __restrict__ Km,
                                                   const ull* __restrict__ Vm,
                                                   float* __restrict__ Y) {
    const int tb = blockIdx.x >> 3;
    const int h = blockIdx.x & 7;
    const int tid = threadIdx.x;
    const int w = tid >> 6;
    const int lane = tid & 63;

    __shared__ ull qrow[256], krow[256], vrow[256];
    __shared__ ull kcol[64][5], vcol[64][5];
    __shared__ ushort G[64][64];
    __shared__ ushort ybuf[196][66];

    const size_t mb = (size_t)tb * 1568 + (size_t)h * 196;
    if (tid < 196) {
        qrow[tid] = Qm[mb + tid];
        krow[tid] = Km[mb + tid];
        vrow[tid] = Vm[mb + tid];
    } else {
        qrow[tid] = 0; krow[tid] = 0; vrow[tid] = 0;
    }
    __syncthreads();

    // Transpose k,v row masks -> column masks (bits over m)
    {
        ull kc = 0, vc = 0;
#pragma unroll 8
        for (int m = 0; m < 64; ++m) {
            kc |= ((krow[w * 64 + m] >> lane) & 1ull) << m;
            vc |= ((vrow[w * 64 + m] >> lane) & 1ull) << m;
        }
        kcol[lane][w] = kc; vcol[lane][w] = vc;
    }
    __syncthreads();

    // G = k^T @ v via popcount (integers <= 196, exact in ushort)
    for (int p = tid; p < 4096; p += 256) {
        const int d1 = p >> 6, d2 = p & 63;
        const int g = __popcll(kcol[d1][0] & vcol[d2][0]) +
                      __popcll(kcol[d1][1] & vcol[d2][1]) +
                      __popcll(kcol[d1][2] & vcol[d2][2]) +
                      __popcll(kcol[d1][3] & vcol[d2][3]);
        G[d1][d2] = (ushort)g;
    }
    __syncthreads();

    // y = q @ G : wave w owns rows [49w, 49w+49); 2 rows share each G read.
    {
        int r = 49 * w;
        const int rend = r + 49;
        for (; r + 1 < rend; r += 2) {
            const ull q0 = qrow[r], q1 = qrow[r + 1];
            const uint a0 = (uint)q0, a1 = (uint)(q0 >> 32);
            const uint b0 = (uint)q1, b1 = (uint)(q1 >> 32);
            uint s0 = 0, s1 = 0;
#pragma unroll
            for (int d = 0; d < 32; ++d) {
                const uint g = G[d][lane];
                s0 += ((a0 >> d) & 1u) * g;
                s1 += ((b0 >> d) & 1u) * g;
            }
#pragma unroll
            for (int d = 0; d < 32; ++d) {
                const uint g = G[32 + d][lane];
                s0 += ((a1 >> d) & 1u) * g;
                s1 += ((b1 >> d) & 1u) * g;
            }
            ybuf[r][lane] = (ushort)s0;
            ybuf[r + 1][lane] = (ushort)s1;
        }
        {   // tail row (49 is odd)
            const ull q0 = qrow[r];
            const uint a0 = (uint)q0, a1 = (uint)(q0 >> 32);
            uint s0 = 0;
#pragma unroll
            for (int d = 0; d < 32; ++d) s0 += ((a0 >> d) & 1u) * (uint)G[d][lane];
#pragma unroll
            for (int d = 0; d < 32; ++d) s0 += ((a1 >> d) & 1u) * (uint)G[32 + d][lane];
            ybuf[r][lane] = (ushort)s0;
        }
    }
    __syncthreads();

    // Coalesced scrambled write: f = e*196 + r within head block
    const size_t yb = (size_t)tb * NC + (size_t)h * 12544;
    for (int f = tid; f < 12544; f += 256) {
        const int e = f / 196;
        const int r = f - e * 196;
        Y[yb + f] = (float)ybuf[r][e] * 0.125f;
    }
}

// ---------------------------------------------------------------------------
// Workspace layout (107,577,344 bytes):
//   u    : fp32 [128][196][512]   51,380,224 B (QKV/proj GEMM out, reused)
//   Qm/Km/Vm : masks [128][8][196] 1,605,632 B each
//   ySc  : fp32 [T][B][N][C]      51,380,224 B (attn out, attn_lif in-place)
// ---------------------------------------------------------------------------
extern "C" void kernel_launch(void* const* d_in, const int* in_sizes, int n_in,
                              void* d_out, int out_size, void* d_ws, size_t ws_size,
                              hipStream_t stream) {
    const float* x  = (const float*)d_in[0];
    const float* Wq = (const float*)d_in[1];
    const float* Wk = (const float*)d_in[2];
    const float* Wv = (const float*)d_in[3];
    const float* Wp = (const float*)d_in[4];
    const float* bp = (const float*)d_in[5];
    const float* wq = (const float*)d_in[6];
    const float* wk = (const float*)d_in[7];
    const float* wv = (const float*)d_in[8];
    const float* wa = (const float*)d_in[9];
    const float* wp = (const float*)d_in[10];
    float* out = (float*)d_out;

    char* ws = (char*)d_ws;
    float* u  = (float*)ws;
    ull* Qm   = (ull*)(ws + 51380224);
    ull* Km   = (ull*)(ws + 51380224 + (size_t)1 * 1605632);
    ull* Vm   = (ull*)(ws + 51380224 + (size_t)2 * 1605632);
    float* ySc = (float*)(ws + 51380224 + (size_t)3 * 1605632);

    const dim3 gGemm(4, 196);  // n fast -> same-A blocks adjacent
    const dim3 b256(256);

    // Q/K/V branches: GEMM -> LIF emitting bitmasks only
    gemm_nt<false><<<gGemm, b256, 0, stream>>>(x, Wq, nullptr, u);
    lif_seq<1><<<392, 256, 0, stream>>>(u, nullptr, Qm, wq, 128, NC);
    gemm_nt<false><<<gGemm, b256, 0, stream>>>(x, Wk, nullptr, u);
    lif_seq<1><<<392, 256, 0, stream>>>(u, nullptr, Km, wk, 128, NC);
    gemm_nt<false><<<gGemm, b256, 0, stream>>>(x, Wv, nullptr, u);
    lif_seq<1><<<392, 256, 0, stream>>>(u, nullptr, Vm, wv, 128, NC);

    // Attention (exact integer path) -> scrambled layout
    attn_kernel<<<1024, 256, 0, stream>>>(Qm, Km, Vm, ySc);

    // attn_lif over T=4 steps, state [B,N,C], in place
    lif_seq<0><<<12544, 256, 0, stream>>>(ySc, ySc, nullptr, wa, 4, BNC);

    // Projection + bias, then proj_lif over 128 steps -> output
    gemm_nt<true><<<gGemm, b256, 0, stream>>>(ySc, Wp, bp, u);
    lif_seq<0><<<392, 256, 0, stream>>>(u, out, nullptr, wp, 128, NC);
}

// Round 3
// 955.085 us; speedup vs baseline: 1.1660x; 1.0591x over previous
//
#include <hip/hip_runtime.h>
#include <hip/hip_bf16.h>

#define NC 100352       // N*C = 196*512
typedef unsigned long long ull;
typedef float (*tile_t)[132];

// ---------------------------------------------------------------------------
// Fused GEMM(+bias) + LIF.
// Block: 128 rows (all tb) x 128 cols (cb) for one n. A rows strided by NC.
// GEMM: double-buffered LDS, BK=16, 8x8 microtile, k-sequential fp32 FMA
// (bit-identical to validated rounds). Then acc -> LDS U-tile (union with
// staging), 128-step LIF recurrence over tb per column.
// PROJ=false: 3 branches (Wq/Wk/Wv) in grid; output = spike bitmasks.
// PROJ=true:  Wp + bias; output = float spikes to `out`.
// ---------------------------------------------------------------------------
template <bool PROJ>
__global__ __launch_bounds__(256) void gemm_lif(
    const float* __restrict__ A,
    const float* __restrict__ W0, const float* __restrict__ W1,
    const float* __restrict__ W2, const float* __restrict__ bias,
    const float* __restrict__ w0, const float* __restrict__ w1,
    const float* __restrict__ w2,
    ull* __restrict__ M, float* __restrict__ out)
{
    __shared__ float U[128][132];          // 67,584 B; rows 0..63 alias staging
    tile_t As0 = (tile_t)&U[0][0];
    tile_t As1 = (tile_t)&U[16][0];
    tile_t Bs0 = (tile_t)&U[32][0];
    tile_t Bs1 = (tile_t)&U[48][0];

    const int bid = blockIdx.x;
    int n, cb, br;
    if (PROJ) {                             // 784 = 8 * 98, XCD-bijective swizzle
        const int work = (bid & 7) * 98 + (bid >> 3);
        n = work >> 2; cb = work & 3; br = 0;
    } else {                                // 2352 = 8 * 294
        const int work = (bid & 7) * 294 + (bid >> 3);
        n = work / 12; const int r12 = work - n * 12;
        br = r12 >> 2; cb = r12 & 3;
    }
    const float* Wb   = PROJ ? W0 : (br == 0 ? W0 : (br == 1 ? W1 : W2));
    const float* wsel = PROJ ? w0 : (br == 0 ? w0 : (br == 1 ? w1 : w2));

    const int tid = threadIdx.x;
    const int r0 = tid >> 2;          // 0..63 : staging row
    const int kq = (tid & 3) << 2;    // 0,4,8,12 : staging k offset
    const int rg = (tid >> 4) << 2;   // compute row base
    const int cg = (tid & 15) << 2;   // compute col base

    const float* Ap0 = A + (size_t)r0 * NC + n * 512 + kq;
    const float* Ap1 = Ap0 + (size_t)64 * NC;
    const float* Wq0 = Wb + (size_t)(cb * 128 + r0) * 512 + kq;
    const float* Wq1 = Wq0 + (size_t)64 * 512;

    float acc[8][8] = {};
    float4 sa0, sa1, sb0, sb1;

    auto LOAD = [&](int k) {
        sa0 = *(const float4*)(Ap0 + k);
        sa1 = *(const float4*)(Ap1 + k);
        sb0 = *(const float4*)(Wq0 + k);
        sb1 = *(const float4*)(Wq1 + k);
    };
    auto STORE = [&](tile_t A_, tile_t B_) {
        A_[kq + 0][r0] = sa0.x; A_[kq + 1][r0] = sa0.y;
        A_[kq + 2][r0] = sa0.z; A_[kq + 3][r0] = sa0.w;
        A_[kq + 0][r0 + 64] = sa1.x; A_[kq + 1][r0 + 64] = sa1.y;
        A_[kq + 2][r0 + 64] = sa1.z; A_[kq + 3][r0 + 64] = sa1.w;
        B_[kq + 0][r0] = sb0.x; B_[kq + 1][r0] = sb0.y;
        B_[kq + 2][r0] = sb0.z; B_[kq + 3][r0] = sb0.w;
        B_[kq + 0][r0 + 64] = sb1.x; B_[kq + 1][r0 + 64] = sb1.y;
        B_[kq + 2][r0 + 64] = sb1.z; B_[kq + 3][r0 + 64] = sb1.w;
    };
    auto COMP = [&](const tile_t A_, const tile_t B_) {
#pragma unroll
        for (int k = 0; k < 16; ++k) {
            float av[8], bv[8];
            *(float4*)&av[0] = *(const float4*)&A_[k][rg];
            *(float4*)&av[4] = *(const float4*)&A_[k][rg + 64];
            *(float4*)&bv[0] = *(const float4*)&B_[k][cg];
            *(float4*)&bv[4] = *(const float4*)&B_[k][cg + 64];
#pragma unroll
            for (int i = 0; i < 8; ++i)
#pragma unroll
                for (int j = 0; j < 8; ++j)
                    acc[i][j] = fmaf(av[i], bv[j], acc[i][j]);
        }
    };

    LOAD(0); STORE(As0, Bs0);
    __syncthreads();
    for (int kk = 0; kk < 512; kk += 32) {
        LOAD(kk + 16);
        COMP(As0, Bs0);
        STORE(As1, Bs1);
        __syncthreads();
        if (kk + 32 < 512) {
            LOAD(kk + 32);
            COMP(As1, Bs1);
            STORE(As0, Bs0);
        } else {
            COMP(As1, Bs1);
        }
        __syncthreads();
    }

    // acc (+bias) -> U tile (overwrites staging area; barrier above protects)
#pragma unroll
    for (int ih = 0; ih < 2; ++ih)
#pragma unroll
        for (int i = 0; i < 4; ++i) {
            const int row = rg + i + ih * 64;
#pragma unroll
            for (int jh = 0; jh < 2; ++jh) {
                float4 o;
                o.x = acc[ih * 4 + i][jh * 4 + 0];
                o.y = acc[ih * 4 + i][jh * 4 + 1];
                o.z = acc[ih * 4 + i][jh * 4 + 2];
                o.w = acc[ih * 4 + i][jh * 4 + 3];
                if (PROJ) {
                    const int colb = cb * 128 + cg + jh * 64;
                    o.x += bias[colb + 0]; o.y += bias[colb + 1];
                    o.z += bias[colb + 2]; o.w += bias[colb + 3];
                }
                *(float4*)&U[row][cg + jh * 64] = o;
            }
        }
    __syncthreads();

    // LIF over tb for each of this block's 128 columns (2 waves active)
    if (tid < 128) {
        const float sg = 1.0f / (1.0f + expf(-wsel[0]));
        const int c = tid, lane = tid & 63;
        const int hglob = cb * 2 + (c >> 6);
        ull* Mw = M + (size_t)br * 200704 + (size_t)hglob * 196 + n;
        float* Ow = out + (size_t)n * 512 + cb * 128 + c;
        float v = 0.0f;
        for (int tb = 0; tb < 128; ++tb) {
            const float uu = U[tb][c];
            const float hh = __fadd_rn(v, __fmul_rn(__fsub_rn(uu, v), sg));
            const bool sp = hh >= 1.0f;
            if (PROJ) {
                Ow[(size_t)tb * NC] = sp ? 1.0f : 0.0f;
            } else {
                const ull mm = __ballot(sp);
                if (lane == 0) Mw[(size_t)tb * 1568] = mm;
            }
            v = sp ? 0.0f : hh;
        }
    }
}

// ---------------------------------------------------------------------------
// Fused attention + attn_lif. Block = (b, h); loop t = 0..3 with LDS v-state.
// Exact integer path (popcount G = k^T v; y = q@G integer mads; *0.125 exact),
// then the _rn LIF recurrence, spikes written scrambled as floats.
// ---------------------------------------------------------------------------
__global__ __launch_bounds__(256) void attn_fused(const ull* __restrict__ Qm,
                                                  const ull* __restrict__ Km,
                                                  const ull* __restrict__ Vm,
                                                  const float* __restrict__ wa,
                                                  float* __restrict__ Y)
{
    const int b = blockIdx.x >> 3;
    const int h = blockIdx.x & 7;
    const int tid = threadIdx.x;
    const int w = tid >> 6;
    const int lane = tid & 63;

    __shared__ ull qrow[256], krow[256], vrow[256];
    __shared__ ull kcol[64][5], vcol[64][5];
    __shared__ ushort G[64][64];
    __shared__ float vstate[196][64];
    __shared__ ull sbm[208];

    const float sg = 1.0f / (1.0f + expf(-wa[0]));

    for (int t = 0; t < 4; ++t) {
        const int tb = t * 32 + b;
        const size_t mb = (size_t)tb * 1568 + (size_t)h * 196;
        if (tid < 196) {
            qrow[tid] = Qm[mb + tid];
            krow[tid] = Km[mb + tid];
            vrow[tid] = Vm[mb + tid];
        } else {
            qrow[tid] = 0; krow[tid] = 0; vrow[tid] = 0;
        }
        __syncthreads();

        {   // transpose k,v row masks -> column masks (bits over m)
            ull kc = 0, vc = 0;
#pragma unroll 8
            for (int m = 0; m < 64; ++m) {
                kc |= ((krow[w * 64 + m] >> lane) & 1ull) << m;
                vc |= ((vrow[w * 64 + m] >> lane) & 1ull) << m;
            }
            kcol[lane][w] = kc; vcol[lane][w] = vc;
        }
        __syncthreads();

        for (int p = tid; p < 4096; p += 256) {
            const int d1 = p >> 6, d2 = p & 63;
            const int g = __popcll(kcol[d1][0] & vcol[d2][0]) +
                          __popcll(kcol[d1][1] & vcol[d2][1]) +
                          __popcll(kcol[d1][2] & vcol[d2][2]) +
                          __popcll(kcol[d1][3] & vcol[d2][3]);
            G[d1][d2] = (ushort)g;
        }
        __syncthreads();

        // y = q @ G (2 rows per G pass) then LIF per row; lane = e.
        {
            int r = 49 * w;
            const int rend = r + 49;
            for (; r + 1 < rend; r += 2) {
                const ull q0 = qrow[r], q1 = qrow[r + 1];
                const uint a0 = (uint)q0, a1 = (uint)(q0 >> 32);
                const uint b0 = (uint)q1, b1 = (uint)(q1 >> 32);
                uint s0 = 0, s1 = 0;
#pragma unroll
                for (int d = 0; d < 32; ++d) {
                    const uint g = G[d][lane];
                    s0 += ((a0 >> d) & 1u) * g;
                    s1 += ((b0 >> d) & 1u) * g;
                }
#pragma unroll
                for (int d = 0; d < 32; ++d) {
                    const uint g = G[32 + d][lane];
                    s0 += ((a1 >> d) & 1u) * g;
                    s1 += ((b1 >> d) & 1u) * g;
                }
                const float y0 = (float)s0 * 0.125f;
                const float v0 = t ? vstate[r][lane] : 0.0f;
                const float h0 = __fadd_rn(v0, __fmul_rn(__fsub_rn(y0, v0), sg));
                const bool sp0 = h0 >= 1.0f;
                vstate[r][lane] = sp0 ? 0.0f : h0;
                const ull m0 = __ballot(sp0);
                const float y1 = (float)s1 * 0.125f;
                const float v1 = t ? vstate[r + 1][lane] : 0.0f;
                const float h1 = __fadd_rn(v1, __fmul_rn(__fsub_rn(y1, v1), sg));
                const bool sp1 = h1 >= 1.0f;
                vstate[r + 1][lane] = sp1 ? 0.0f : h1;
                const ull m1 = __ballot(sp1);
                if (lane == 0) { sbm[r] = m0; sbm[r + 1] = m1; }
            }
            {   // tail row (49 odd)
                const ull q0 = qrow[r];
                const uint a0 = (uint)q0, a1 = (uint)(q0 >> 32);
                uint s0 = 0;
#pragma unroll
                for (int d = 0; d < 32; ++d) s0 += ((a0 >> d) & 1u) * (uint)G[d][lane];
#pragma unroll
                for (int d = 0; d < 32; ++d) s0 += ((a1 >> d) & 1u) * (uint)G[32 + d][lane];
                const float y0 = (float)s0 * 0.125f;
                const float v0 = t ? vstate[r][lane] : 0.0f;
                const float h0 = __fadd_rn(v0, __fmul_rn(__fsub_rn(y0, v0), sg));
                const bool sp0 = h0 >= 1.0f;
                vstate[r][lane] = sp0 ? 0.0f : h0;
                const ull m0 = __ballot(sp0);
                if (lane == 0) sbm[r] = m0;
            }
        }
        __syncthreads();

        // Coalesced scrambled spike write: f = e*196 + r within head block
        const size_t yb = (size_t)tb * NC + (size_t)h * 12544;
        for (int f = tid; f < 12544; f += 256) {
            const int e = f / 196;
            const int r2 = f - e * 196;
            Y[yb + f] = ((sbm[r2] >> e) & 1ull) ? 1.0f : 0.0f;
        }
        __syncthreads();
    }
}

// ---------------------------------------------------------------------------
// Workspace (56,197,120 B):
//   Qm/Km/Vm : masks [128][8][196] ull, 1,605,632 B each (contiguous)
//   ySc      : fp32 spikes [T][B][N][C] scrambled, 51,380,224 B
// ---------------------------------------------------------------------------
extern "C" void kernel_launch(void* const* d_in, const int* in_sizes, int n_in,
                              void* d_out, int out_size, void* d_ws, size_t ws_size,
                              hipStream_t stream) {
    const float* x  = (const float*)d_in[0];
    const float* Wq = (const float*)d_in[1];
    const float* Wk = (const float*)d_in[2];
    const float* Wv = (const float*)d_in[3];
    const float* Wp = (const float*)d_in[4];
    const float* bp = (const float*)d_in[5];
    const float* wq = (const float*)d_in[6];
    const float* wk = (const float*)d_in[7];
    const float* wv = (const float*)d_in[8];
    const float* wa = (const float*)d_in[9];
    const float* wp = (const float*)d_in[10];
    float* out = (float*)d_out;

    char* ws = (char*)d_ws;
    ull* Qm = (ull*)ws;                               // + br*200704 words inside
    ull* Km = Qm + 200704;
    ull* Vm = Km + 200704;
    float* ySc = (float*)(ws + (size_t)3 * 1605632);

    // Q/K/V: fused GEMM+LIF -> bitmasks (one dispatch, 3 branches in grid)
    gemm_lif<false><<<2352, 256, 0, stream>>>(x, Wq, Wk, Wv, nullptr,
                                              wq, wk, wv, Qm, nullptr);

    // Attention + attn_lif -> scrambled float spikes
    attn_fused<<<256, 256, 0, stream>>>(Qm, Km, Vm, wa, ySc);

    // Projection + bias + proj_lif -> output spikes
    gemm_lif<true><<<784, 256, 0, stream>>>(ySc, Wp, nullptr, nullptr, bp,
                                            wp, nullptr, nullptr, nullptr, out);
}